// Round 4
// baseline (12300.048 us; speedup 1.0000x reference)
//
#include <hip/hip_runtime.h>
#include <hip/hip_fp16.h>
#include <stdint.h>

// ---------------------------------------------------------------------------
// GPT forward, MI355X. Round 4: fix OUTPUT dtype.
//  - Round 3's absmax 2.664 = sqrt(2) * 1.875 (= stub-round max|ref|):
//    output uncorrelated-but-same-distribution => d_out was being read as
//    FP32 while we wrote packed bf16. Harness doc: d_out is the REFERENCE's
//    output dtype = float32. Round 2's NaN = bf16 NaNs read as fp32 pairs.
//  - Inputs proven fp32 (round-3 detection removed the misparse NaN).
//  - Change: LM-head epilogue writes fp32 (FOUT flag). Rest unchanged.
// Structure: ws-adaptive batch chunking; bf16 MFMA 16x16x32, 128x128x32
// tiles (layouts match AMD matrix calculator); fp32 residual stream.
// ---------------------------------------------------------------------------

typedef unsigned short u16;
typedef __bf16 bf16x8 __attribute__((ext_vector_type(8)));
typedef float f32x4 __attribute__((ext_vector_type(4)));

#define M_TOK 131072   // B*T
#define CDIM  384
#define TT    32
#define HH    6
#define DHEAD 64
#define LLAY  6
#define VOCAB 80
#define FFDIM 1536
#define QKVN  1152

__device__ __forceinline__ float b2f(u16 v) {
    union { unsigned int u; float f; } x; x.u = ((unsigned int)v) << 16; return x.f;
}
__device__ __forceinline__ u16 f2b(float f) {
    union { float f; unsigned int u; } x; x.f = f;
    unsigned int r = (x.u + 0x7fffu + ((x.u >> 16) & 1u)) >> 16;   // RNE
    return (u16)r;
}
// mode: 0 = fp32, 1 = bf16, 2 = fp16
__device__ __forceinline__ float load_in(const void* p, size_t i, int m) {
    if (m == 0) return ((const float*)p)[i];
    u16 v = ((const u16*)p)[i];
    if (m == 1) return b2f(v);
    __half h; *(u16*)&h = v; return __half2float(h);
}

// --------------------------- dtype detection -------------------------------
__global__ void detect_dtype_kernel(const void* ln1g, int* flag) {
    if (threadIdx.x == 0 && blockIdx.x == 0) {
        unsigned w = *(const unsigned*)ln1g;       // ln1_g is all 1.0
        int m = 0;
        if (w == 0x3F803F80u) m = 1;               // bf16 ones
        else if (w == 0x3C003C00u) m = 2;          // fp16 ones
        *flag = m;
    }
}

// --------------------------- param convert ---------------------------------
__global__ void cvt_kernel(const void* __restrict__ src, u16* __restrict__ dst,
                           unsigned n, const int* __restrict__ flag) {
    const int m = *flag;
    unsigned i = blockIdx.x * 256 + threadIdx.x;
    if (i < n) dst[i] = f2b(load_in(src, i, m));
}

// --------------------------- weight repack ---------------------------------
// dst [L][Cc][R] = src [L][R][Cc] transposed per layer (B^T layout for GEMM)
__global__ void transpose_kernel(const void* __restrict__ src, u16* __restrict__ dst,
                                 int R, int Cc, unsigned total,
                                 const int* __restrict__ flag) {
    const int m = *flag;
    unsigned i = blockIdx.x * 256 + threadIdx.x;
    if (i >= total) return;
    unsigned c  = i % R;
    unsigned t2 = i / R;
    unsigned n  = t2 % Cc;
    unsigned l  = t2 / Cc;
    dst[i] = f2b(load_in(src, ((size_t)l * R + c) * Cc + n, m));
}

// dst[l][n][c] (n in [0,1152)): n<384 -> Wq[l][n>>6][c][n&63]; then Wk; then Wv
__global__ void pack_qkv_kernel(const void* __restrict__ Wq, const void* __restrict__ Wk,
                                const void* __restrict__ Wv, u16* __restrict__ dst,
                                const int* __restrict__ flag) {
    const int m = *flag;
    unsigned i = blockIdx.x * 256 + threadIdx.x;
    const unsigned total = (unsigned)LLAY * QKVN * CDIM;
    if (i >= total) return;
    unsigned c  = i % CDIM;
    unsigned t2 = i / CDIM;
    unsigned n  = t2 % QKVN;
    unsigned l  = t2 / QKVN;
    const void* W = (n < 384) ? Wq : (n < 768) ? Wk : Wv;
    unsigned nn = n % 384;
    unsigned hh = nn >> 6, d = nn & 63;
    dst[i] = f2b(load_in(W, (((size_t)l * HH + hh) * CDIM + c) * DHEAD + d, m));
}

// ------------------------------- embedding ---------------------------------
__global__ void embed_kernel(const int* __restrict__ idx, const void* __restrict__ tok,
                             const void* __restrict__ pos, float* __restrict__ x,
                             unsigned rows0, const int* __restrict__ flag) {
    const int m = *flag;
    unsigned i = blockIdx.x * 256 + threadIdx.x;
    unsigned c  = i % CDIM;
    unsigned bt = i / CDIM + rows0;
    unsigned t  = bt & (TT - 1);
    int id = idx[bt];
    x[i] = load_in(tok, (size_t)id * CDIM + c, m) + load_in(pos, (size_t)t * CDIM + c, m);
}

// ------------------------------- layernorm ---------------------------------
// one wave per row (C=384 = 64 lanes * 6); x fp32 in, bf16 out; g/b bf16 (pbuf)
__global__ __launch_bounds__(256) void ln_kernel(const float* __restrict__ x,
                                                 const u16* __restrict__ g,
                                                 const u16* __restrict__ b,
                                                 u16* __restrict__ out) {
    const unsigned row  = blockIdx.x * 4 + (threadIdx.x >> 6);
    const unsigned lane = threadIdx.x & 63;
    const float* xr = x + (size_t)row * CDIM;
    float v[6]; float s = 0.f, s2 = 0.f;
#pragma unroll
    for (int j = 0; j < 6; j++) { v[j] = xr[lane + j * 64]; s += v[j]; s2 += v[j] * v[j]; }
#pragma unroll
    for (int off = 32; off; off >>= 1) { s += __shfl_xor(s, off); s2 += __shfl_xor(s2, off); }
    float mean = s * (1.f / CDIM);
    float var  = fmaxf(s2 * (1.f / CDIM) - mean * mean, 0.f);
    float rstd = rsqrtf(var + 1e-5f);
    u16* orow = out + (size_t)row * CDIM;
#pragma unroll
    for (int j = 0; j < 6; j++) {
        unsigned c = lane + j * 64;
        orow[c] = f2b((v[j] - mean) * rstd * b2f(g[c]) + b2f(b[c]));
    }
}

// --------------------------------- GEMM ------------------------------------
// C[M,N] = A[M,K] @ B[K,N], B given transposed (Bt[N,K]). bf16 in, fp32 acc.
// BIAS adds bias[N] (bf16); RELU; RESID: Cf = resid + acc (fp32, may alias
// resid); FOUT: Cf = acc (fp32, no resid); else Cb = bf16.
// NBOUND: N not multiple of 128 (LM head, N=80).
template<bool BIAS, bool RELU, bool RESID, bool NBOUND, bool FOUT>
__global__ __launch_bounds__(256)
void gemm_kernel(const u16* __restrict__ A, const u16* __restrict__ Bt,
                 const u16* __restrict__ bias, const float* resid,
                 u16* __restrict__ Cb, float* Cf,
                 int N, int K) {
    __shared__ __align__(16) u16 As[128 * 32];
    __shared__ __align__(16) u16 Bs[128 * 32];
    const int tid  = threadIdx.x;
    const int lane = tid & 63;
    const int wave = tid >> 6;
    const int quad = lane >> 4;
    const int l16  = lane & 15;
    const int wm = wave >> 1, wn = wave & 1;

    const long m0 = (long)blockIdx.y * 128;
    const long n0 = (long)blockIdx.x * 128;

    const int ar = tid >> 1;          // tile row handled by this thread (0..127)
    const int ac = (tid & 1) * 16;    // col chunk (0 or 16)

    const u16* Ag = A + (m0 + ar) * K + ac;
    bool bok = true;
    long brow = n0 + ar;
    if (NBOUND) bok = (brow < N);
    const u16* Bg = Bt + (bok ? brow : 0) * K + ac;

    f32x4 acc[4][4];
#pragma unroll
    for (int i = 0; i < 4; i++)
#pragma unroll
        for (int j = 0; j < 4; j++) acc[i][j] = f32x4{0.f, 0.f, 0.f, 0.f};

    for (int k0 = 0; k0 < K; k0 += 32) {
        uint4 av0 = *(const uint4*)(Ag);
        uint4 av1 = *(const uint4*)(Ag + 8);
        uint4 bv0, bv1;
        if (!NBOUND || bok) { bv0 = *(const uint4*)(Bg); bv1 = *(const uint4*)(Bg + 8); }
        else                { bv0 = make_uint4(0, 0, 0, 0); bv1 = bv0; }
        __syncthreads();   // previous iteration's LDS reads complete
        *(uint4*)(&As[ar * 32 + ac])     = av0;
        *(uint4*)(&As[ar * 32 + ac + 8]) = av1;
        *(uint4*)(&Bs[ar * 32 + ac])     = bv0;
        *(uint4*)(&Bs[ar * 32 + ac + 8]) = bv1;
        __syncthreads();
        bf16x8 af[4], bfr[4];
#pragma unroll
        for (int i = 0; i < 4; i++)
            af[i] = *(const bf16x8*)(&As[(wm * 64 + i * 16 + l16) * 32 + quad * 8]);
#pragma unroll
        for (int j = 0; j < 4; j++)
            bfr[j] = *(const bf16x8*)(&Bs[(wn * 64 + j * 16 + l16) * 32 + quad * 8]);
#pragma unroll
        for (int i = 0; i < 4; i++)
#pragma unroll
            for (int j = 0; j < 4; j++)
                acc[i][j] = __builtin_amdgcn_mfma_f32_16x16x32_bf16(af[i], bfr[j], acc[i][j], 0, 0, 0);
        Ag += 32; Bg += 32;
    }

    // epilogue: C/D layout col = lane&15, row = quad*4 + reg
#pragma unroll
    for (int j = 0; j < 4; j++) {
        const int col = (int)n0 + wn * 64 + j * 16 + l16;
        float bv = 0.f;
        if (BIAS) bv = (!NBOUND || col < N) ? b2f(bias[col]) : 0.f;
#pragma unroll
        for (int i = 0; i < 4; i++) {
#pragma unroll
            for (int r = 0; r < 4; r++) {
                const long row = m0 + wm * 64 + i * 16 + quad * 4 + r;
                float v = acc[i][j][r] + bv;
                if (RELU) v = fmaxf(v, 0.f);
                if (RESID) {
                    Cf[row * N + col] = resid[row * N + col] + v;
                } else if (FOUT) {
                    if (!NBOUND || col < N) Cf[row * N + col] = v;
                } else {
                    if (!NBOUND || col < N) Cb[row * N + col] = f2b(v);
                }
            }
        }
    }
}

// ------------------------------- attention ---------------------------------
// one block per sequence; thread = (h, t); fp32 softmax; causal T=32, DH=64.
// qkv: [rows][1152] bf16 (q | k | v, head-major within each 384 chunk)
__global__ __launch_bounds__(192) void attn_kernel(const u16* __restrict__ qkv,
                                                   u16* __restrict__ o) {
    const int b = blockIdx.x;
    const int h = threadIdx.x >> 5;
    const int t = threadIdx.x & 31;
    const u16* base = qkv + (size_t)b * TT * QKVN;
    const u16* qr = base + t * QKVN + h * DHEAD;
    float q[DHEAD];
#pragma unroll
    for (int d = 0; d < DHEAD; d++) q[d] = b2f(qr[d]);

    float sc[TT];
    float mx = -1e30f;
#pragma unroll
    for (int s = 0; s < TT; s++) {
        if (s <= t) {
            const u16* kr = base + s * QKVN + 384 + h * DHEAD;
            float dot = 0.f;
#pragma unroll
            for (int d = 0; d < DHEAD; d++) dot += q[d] * b2f(kr[d]);
            sc[s] = dot * 0.125f;            // DH^-0.5
            mx = fmaxf(mx, sc[s]);
        } else sc[s] = -1e30f;
    }
    float sum = 0.f;
#pragma unroll
    for (int s = 0; s < TT; s++) { sc[s] = __expf(sc[s] - mx); sum += sc[s]; }
    float inv = 1.f / sum;

    float oacc[DHEAD];
#pragma unroll
    for (int d = 0; d < DHEAD; d++) oacc[d] = 0.f;
#pragma unroll
    for (int s = 0; s < TT; s++) {
        if (s <= t) {
            float p = sc[s] * inv;
            const u16* vr = base + s * QKVN + 768 + h * DHEAD;
#pragma unroll
            for (int d = 0; d < DHEAD; d++) oacc[d] += p * b2f(vr[d]);
        }
    }
    u16* orow = o + ((size_t)b * TT + t) * CDIM + h * DHEAD;
#pragma unroll
    for (int d = 0; d < DHEAD; d++) orow[d] = f2b(oacc[d]);
}

// ------------------------------- launcher ----------------------------------
extern "C" void kernel_launch(void* const* d_in, const int* in_sizes, int n_in,
                              void* d_out, int out_size, void* d_ws, size_t ws_size,
                              hipStream_t stream) {
    const int*  idx  = (const int*)d_in[0];
    const void* tok  = d_in[1];
    const void* pos  = d_in[2];
    const void* ln1g = d_in[3];
    const void* ln1b = d_in[4];
    const void* Wq   = d_in[5];
    const void* Wk   = d_in[6];
    const void* Wv   = d_in[7];
    const void* Wo   = d_in[8];
    const void* bo   = d_in[9];
    const void* ln2g = d_in[10];
    const void* ln2b = d_in[11];
    const void* W1   = d_in[12];
    const void* b1   = d_in[13];
    const void* W2   = d_in[14];
    const void* b2   = d_in[15];
    const void* lnfg = d_in[16];
    const void* lnfb = d_in[17];
    const void* Wlm  = d_in[18];
    const void* blm  = d_in[19];

    // ---- workspace layout (adaptive batch chunking) ----
    const size_t wq_b  = (size_t)LLAY * QKVN * CDIM * 2;
    const size_t wo_b  = (size_t)LLAY * CDIM * CDIM * 2;
    const size_t w1_b  = (size_t)LLAY * FFDIM * CDIM * 2;
    const size_t w2_b  = (size_t)LLAY * CDIM * FFDIM * 2;
    const size_t wlm_b = (size_t)VOCAB * CDIM * 2;
    const size_t wts   = wq_b + wo_b + w1_b + w2_b + wlm_b;   // ~21.3 MB

    // pbuf: converted 1-D params, bf16 elements
    const unsigned P_LN1G = 0,      P_LN1B = 2304,  P_BO  = 4608;
    const unsigned P_LN2G = 6912,   P_LN2B = 9216,  P_B1  = 11520;
    const unsigned P_B2   = 20736,  P_LNFG = 23040, P_LNFB = 23424;
    const unsigned P_BLM  = 23808,  P_TOT  = 23888;
    const size_t pbuf_b = ((size_t)P_TOT * 2 + 255) & ~(size_t)255;

    // per-row bytes: x fp32 1536 + h bf16 768 + S (max(qkv+o, u)) 3072 = 5376
    int NC = 32;
    {
        const int cand[6] = {1, 2, 4, 8, 16, 32};
        for (int ci = 0; ci < 6; ci++) {
            size_t rows_c = (size_t)M_TOK / cand[ci];
            size_t need = rows_c * 5376 + wts + pbuf_b + 4096;
            if (need <= ws_size) { NC = cand[ci]; break; }
        }
    }
    const size_t rows = (size_t)M_TOK / NC;

    char* ws = (char*)d_ws;
    size_t off = 0;
    float* x    = (float*)(ws + off); off += rows * CDIM * 4;         // fp32 residual
    u16*   h    = (u16*)(ws + off);   off += rows * CDIM * 2;         // LN out
    char*  S    = ws + off;           off += rows * 3072;             // shared scratch
    u16*   qkv  = (u16*)S;                                            // rows*1152 bf16
    u16*   o    = (u16*)(S + rows * QKVN * 2);                        // rows*384 bf16
    u16*   u    = (u16*)S;                                            // rows*1536 bf16 (qkv,o dead)
    u16* wqkvT  = (u16*)(ws + off);   off += wq_b;
    u16* woT    = (u16*)(ws + off);   off += wo_b;
    u16* w1T    = (u16*)(ws + off);   off += w1_b;
    u16* w2T    = (u16*)(ws + off);   off += w2_b;
    u16* wlmT   = (u16*)(ws + off);   off += wlm_b;
    u16* pbuf   = (u16*)(ws + off);   off += pbuf_b;
    int* flag   = (int*)(ws + off);   off += 256;

    // ---- dtype detect + param convert + weight repack (once per call) ----
    detect_dtype_kernel<<<1, 64, 0, stream>>>(ln1g, flag);

    struct { const void* src; unsigned doff, n; } cv[10] = {
        { ln1g, P_LN1G, 2304 }, { ln1b, P_LN1B, 2304 }, { bo, P_BO, 2304 },
        { ln2g, P_LN2G, 2304 }, { ln2b, P_LN2B, 2304 }, { b1, P_B1, 9216 },
        { b2,   P_B2,   2304 }, { lnfg, P_LNFG, 384 },  { lnfb, P_LNFB, 384 },
        { blm,  P_BLM,  80 },
    };
    for (int i = 0; i < 10; i++)
        cvt_kernel<<<(cv[i].n + 255) / 256, 256, 0, stream>>>(cv[i].src, pbuf + cv[i].doff, cv[i].n, flag);

    {
        unsigned tq = (unsigned)LLAY * QKVN * CDIM;
        pack_qkv_kernel<<<(tq + 255) / 256, 256, 0, stream>>>(Wq, Wk, Wv, wqkvT, flag);
        unsigned t1 = (unsigned)LLAY * CDIM * CDIM;
        transpose_kernel<<<(t1 + 255) / 256, 256, 0, stream>>>(Wo, woT, CDIM, CDIM, t1, flag);
        unsigned t2t = (unsigned)LLAY * CDIM * FFDIM;
        transpose_kernel<<<(t2t + 255) / 256, 256, 0, stream>>>(W1, w1T, CDIM, FFDIM, t2t, flag);
        transpose_kernel<<<(t2t + 255) / 256, 256, 0, stream>>>(W2, w2T, FFDIM, CDIM, t2t, flag);
        unsigned t3 = (unsigned)VOCAB * CDIM;
        transpose_kernel<<<(t3 + 255) / 256, 256, 0, stream>>>(Wlm, wlmT, CDIM, VOCAB, t3, flag);
    }

    // ---- batch-chunked forward ----
    for (int c = 0; c < NC; c++) {
        const size_t r0 = c * rows;            // first token-row of chunk
        embed_kernel<<<(rows * CDIM) / 256, 256, 0, stream>>>(idx, tok, pos, x, (unsigned)r0, flag);

        for (int l = 0; l < LLAY; l++) {
            ln_kernel<<<rows / 4, 256, 0, stream>>>(x, pbuf + P_LN1G + l * CDIM, pbuf + P_LN1B + l * CDIM, h);
            gemm_kernel<false, false, false, false, false><<<dim3(QKVN / 128, rows / 128), 256, 0, stream>>>(
                h, wqkvT + (size_t)l * QKVN * CDIM, nullptr, nullptr, qkv, nullptr, QKVN, CDIM);
            attn_kernel<<<rows / TT, 192, 0, stream>>>(qkv, o);
            gemm_kernel<true, false, true, false, false><<<dim3(CDIM / 128, rows / 128), 256, 0, stream>>>(
                o, woT + (size_t)l * CDIM * CDIM, pbuf + P_BO + l * CDIM, x, nullptr, x, CDIM, CDIM);
            ln_kernel<<<rows / 4, 256, 0, stream>>>(x, pbuf + P_LN2G + l * CDIM, pbuf + P_LN2B + l * CDIM, h);
            gemm_kernel<true, true, false, false, false><<<dim3(FFDIM / 128, rows / 128), 256, 0, stream>>>(
                h, w1T + (size_t)l * FFDIM * CDIM, pbuf + P_B1 + l * FFDIM, nullptr, u, nullptr, FFDIM, CDIM);
            gemm_kernel<true, false, true, false, false><<<dim3(CDIM / 128, rows / 128), 256, 0, stream>>>(
                u, w2T + (size_t)l * CDIM * FFDIM, pbuf + P_B2 + l * CDIM, x, nullptr, x, CDIM, FFDIM);
        }

        ln_kernel<<<rows / 4, 256, 0, stream>>>(x, pbuf + P_LNFG, pbuf + P_LNFB, h);
        gemm_kernel<true, false, false, true, true><<<dim3(1, rows / 128), 256, 0, stream>>>(
            h, wlmT, pbuf + P_BLM, nullptr, nullptr, (float*)d_out + r0 * VOCAB, VOCAB, CDIM);
    }
}